// Round 6
// baseline (310.439 us; speedup 1.0000x reference)
//
#include <hip/hip_runtime.h>
#include <hip/hip_bf16.h>
#include <math.h>

#define SCALE_ 0.04419417382415922f   // 512^-0.5
#define EPS_  1e-5f

typedef unsigned short u16;
typedef __attribute__((ext_vector_type(8))) short     bf16x8;
typedef __attribute__((ext_vector_type(4))) float     f32x4;
typedef __attribute__((ext_vector_type(8))) unsigned short u16x8;
typedef __attribute__((ext_vector_type(4))) unsigned short u16x4;

__device__ __forceinline__ u16 f2b(float f) {
  union { float f; unsigned int u; } x; x.f = f;
  unsigned int u = x.u;
  return (u16)((u + 0x7FFFu + ((u >> 16) & 1u)) >> 16);
}
__device__ __forceinline__ float b2f(u16 h) {
  union { unsigned int u; float f; } x; x.u = ((unsigned int)h) << 16;
  return x.f;
}
__device__ __forceinline__ void gload_lds16(const void* g, void* l) {
  __builtin_amdgcn_global_load_lds(
      (const __attribute__((address_space(1))) void*)g,
      (__attribute__((address_space(3))) void*)l, 16, 0, 0);
}

// ---------------------------------------------------------------------------
// Weight convert+transpose: Wt[n][k] = bf16(W[k][n]), 512x512, z selects weight
// ---------------------------------------------------------------------------
__global__ __launch_bounds__(256) void wconv(
    const float* W0, const float* W1, const float* W2,
    const float* W3, const float* W4, const float* W5, u16* wt)
{
  const float* W;
  switch (blockIdx.z) {
    case 0: W = W0; break; case 1: W = W1; break; case 2: W = W2; break;
    case 3: W = W3; break; case 4: W = W4; break; default: W = W5; break;
  }
  u16* Wt = wt + (size_t)blockIdx.z * 262144;
  const int k0 = blockIdx.x * 64, n0 = blockIdx.y * 64;
  __shared__ float T[64][68];
  const int tid = threadIdx.x;
#pragma unroll
  for (int it = 0; it < 4; ++it) {
    int L = it * 256 + tid;
    int r = L >> 4, cg = L & 15;
    float4 v = *reinterpret_cast<const float4*>(W + (size_t)(k0 + r) * 512 + n0 + cg * 4);
    T[r][cg * 4 + 0] = v.x; T[r][cg * 4 + 1] = v.y;
    T[r][cg * 4 + 2] = v.z; T[r][cg * 4 + 3] = v.w;
  }
  __syncthreads();
#pragma unroll
  for (int it = 0; it < 2; ++it) {
    int L = it * 256 + tid;
    int rn = L >> 3, kg = L & 7;
    u16x8 o;
#pragma unroll
    for (int e = 0; e < 8; ++e) o[e] = f2b(T[kg * 8 + e][rn]);
    *(u16x8*)(Wt + (size_t)(n0 + rn) * 512 + k0 + kg * 8) = o;
  }
}

// ---------------------------------------------------------------------------
// Strip projection GEMM with async-split schedule (T14):
// C_bf16[128 x 512 strip] = bf16(A_f32) @ Bt^T + bias.  BK=64, single buffer.
// Per iter: [issue A(t+1) f32 loads] -> compute(t) -> barrier ->
//           [cvt+ds_write A(t+1); gload_lds B(t+1)] -> barrier.
// A HBM latency hides under the compute phase; B is L2-resident (512KB).
// ---------------------------------------------------------------------------
__global__ __launch_bounds__(512) void gemm_proj(
    const float* A0, const u16* Bt0, const float* bi0, u16* C0,
    const float* A1, const u16* Bt1, const float* bi1, u16* C1,
    const float* A2, const u16* Bt2, const float* bi2, u16* C2)
{
  const float *A, *bias; const u16* Bt; u16* C;
  if (blockIdx.z == 0)      { A = A0; Bt = Bt0; bias = bi0; C = C0; }
  else if (blockIdx.z == 1) { A = A1; Bt = Bt1; bias = bi1; C = C1; }
  else                      { A = A2; Bt = Bt2; bias = bi2; C = C2; }

  __shared__ u16 As[8192];    // 128 rows x 64 k
  __shared__ u16 Bs[32768];   // 512 n-rows x 64 k
  const int tid = threadIdx.x;
  const int lane = tid & 63, wid = tid >> 6;
  const int wr = wid >> 2, wcn = wid & 3;          // 2 x 4 wave grid
  const int l15 = lane & 15, lh = lane >> 4, l7 = lane & 7;
  const int m0 = blockIdx.x * 128;

  const f32x4 fz = {0.f, 0.f, 0.f, 0.f};
  f32x4 acc[4][8];
#pragma unroll
  for (int m = 0; m < 4; ++m)
#pragma unroll
    for (int n = 0; n < 8; ++n) acc[m][n] = fz;

  int aoff[2], boff[2];
#pragma unroll
  for (int kh = 0; kh < 2; ++kh) {
    int slot = ((kh * 4 + lh) ^ l7) << 4;
    aoff[kh] = (wr * 64 + l15) * 128 + slot;
    boff[kh] = (wcn * 128 + l15) * 128 + slot;
  }

  float4 xa[2], xb[2];
  // prologue: tile 0
#pragma unroll
  for (int it = 0; it < 2; ++it) {
    int L = it * 512 + tid;
    int r = L >> 3, s = L & 7;
    int c = s ^ (r & 7);
    const float* ga = A + (size_t)(m0 + r) * 512 + c * 8;
    xa[it] = *reinterpret_cast<const float4*>(ga);
    xb[it] = *reinterpret_cast<const float4*>(ga + 4);
  }
#pragma unroll
  for (int it = 0; it < 8; ++it) {
    int L = it * 512 + tid;
    int r = L >> 3, s = L & 7;
    int c = s ^ (r & 7);
    gload_lds16(Bt + (size_t)r * 512 + c * 8, (char*)Bs + L * 16);
  }
#pragma unroll
  for (int it = 0; it < 2; ++it) {
    int L = it * 512 + tid;
    u16x8 o;
    o[0] = f2b(xa[it].x); o[1] = f2b(xa[it].y);
    o[2] = f2b(xa[it].z); o[3] = f2b(xa[it].w);
    o[4] = f2b(xb[it].x); o[5] = f2b(xb[it].y);
    o[6] = f2b(xb[it].z); o[7] = f2b(xb[it].w);
    *(u16x8*)((char*)As + L * 16) = o;
  }
  __syncthreads();

  for (int t = 0; t < 8; ++t) {
    // issue A loads for t+1 early — latency spans the compute phase
    if (t < 7) {
      const int kn = (t + 1) * 64;
#pragma unroll
      for (int it = 0; it < 2; ++it) {
        int L = it * 512 + tid;
        int r = L >> 3, s = L & 7;
        int c = s ^ (r & 7);
        const float* ga = A + (size_t)(m0 + r) * 512 + kn + c * 8;
        xa[it] = *reinterpret_cast<const float4*>(ga);
        xb[it] = *reinterpret_cast<const float4*>(ga + 4);
      }
    }
    // compute tile t
#pragma unroll
    for (int kh = 0; kh < 2; ++kh) {
      bf16x8 af[4], bfr[8];
#pragma unroll
      for (int m = 0; m < 4; ++m)
        af[m] = *(const bf16x8*)((const char*)As + aoff[kh] + m * 2048);
#pragma unroll
      for (int n = 0; n < 8; ++n)
        bfr[n] = *(const bf16x8*)((const char*)Bs + boff[kh] + n * 2048);
#pragma unroll
      for (int m = 0; m < 4; ++m)
#pragma unroll
        for (int n = 0; n < 8; ++n)
          acc[m][n] = __builtin_amdgcn_mfma_f32_16x16x32_bf16(af[m], bfr[n], acc[m][n], 0, 0, 0);
    }
    if (t < 7) {
      __syncthreads();          // all waves done reading As/Bs
      const int kn = (t + 1) * 64;
#pragma unroll
      for (int it = 0; it < 2; ++it) {
        int L = it * 512 + tid;
        u16x8 o;
        o[0] = f2b(xa[it].x); o[1] = f2b(xa[it].y);
        o[2] = f2b(xa[it].z); o[3] = f2b(xa[it].w);
        o[4] = f2b(xb[it].x); o[5] = f2b(xb[it].y);
        o[6] = f2b(xb[it].z); o[7] = f2b(xb[it].w);
        *(u16x8*)((char*)As + L * 16) = o;
      }
#pragma unroll
      for (int it = 0; it < 8; ++it) {
        int L = it * 512 + tid;
        int r = L >> 3, s = L & 7;
        int c = s ^ (r & 7);
        gload_lds16(Bt + (size_t)r * 512 + kn + c * 8, (char*)Bs + L * 16);
      }
      __syncthreads();          // publish tile t+1
    }
  }

  const int gn0 = wcn * 128 + l15;
  float bv[8];
#pragma unroll
  for (int n = 0; n < 8; ++n) bv[n] = bias[gn0 + n * 16];
#pragma unroll
  for (int m = 0; m < 4; ++m)
#pragma unroll
    for (int reg = 0; reg < 4; ++reg) {
      int gm = m0 + wr * 64 + m * 16 + lh * 4 + reg;
#pragma unroll
      for (int n = 0; n < 8; ++n)
        C[(size_t)gm * 512 + gn0 + n * 16] = f2b(acc[m][n][reg] + bv[n]);
    }
}

// ---------------------------------------------------------------------------
// Strip output GEMM, double-buffered: out_f32 = A_bf16 @ Bt^T + bias.
// ---------------------------------------------------------------------------
__global__ __launch_bounds__(512) void gemm_out(
    const u16* __restrict__ A, const u16* __restrict__ Bt,
    const float* __restrict__ bias, float* __restrict__ C)
{
  __shared__ u16 As[2][4096];
  __shared__ u16 Bs[2][16384];
  const int tid = threadIdx.x;
  const int lane = tid & 63, wid = tid >> 6;
  const int wr = wid >> 2, wcn = wid & 3;
  const int l15 = lane & 15, lh = lane >> 4;
  const int sx = (l15 >> 1) & 3;
  const int m0 = blockIdx.x * 128;
  const int rr = tid >> 2, sp = tid & 3;
  const int ssw = sp ^ ((rr >> 1) & 3);

  const f32x4 fz = {0.f, 0.f, 0.f, 0.f};
  f32x4 acc[4][8];
#pragma unroll
  for (int m = 0; m < 4; ++m)
#pragma unroll
    for (int n = 0; n < 8; ++n) acc[m][n] = fz;

  const int aoff0 = (wr * 64 + l15) * 64 + ((lh ^ sx) << 4);
  const int boff0 = (wcn * 128 + l15) * 64 + ((lh ^ sx) << 4);

  {
#pragma unroll
    for (int it = 0; it < 4; ++it)
      gload_lds16(Bt + (size_t)(it * 128 + rr) * 512 + ssw * 8,
                  (char*)Bs[0] + (it * 512 + wid * 64) * 16);
    gload_lds16(A + (size_t)(m0 + rr) * 512 + ssw * 8,
                (char*)As[0] + (wid * 64) * 16);
  }
  __syncthreads();

#pragma unroll 2
  for (int t = 0; t < 16; ++t) {
    const int cur = t & 1, nxt = cur ^ 1;
    if (t < 15) {
      const int k0 = (t + 1) * 32;
#pragma unroll
      for (int it = 0; it < 4; ++it)
        gload_lds16(Bt + (size_t)(it * 128 + rr) * 512 + k0 + ssw * 8,
                    (char*)Bs[nxt] + (it * 512 + wid * 64) * 16);
      gload_lds16(A + (size_t)(m0 + rr) * 512 + k0 + ssw * 8,
                  (char*)As[nxt] + (wid * 64) * 16);
    }
    bf16x8 af[4], bfr[8];
#pragma unroll
    for (int m = 0; m < 4; ++m)
      af[m] = *(const bf16x8*)((const char*)As[cur] + aoff0 + m * 1024);
#pragma unroll
    for (int n = 0; n < 8; ++n)
      bfr[n] = *(const bf16x8*)((const char*)Bs[cur] + boff0 + n * 1024);
#pragma unroll
    for (int m = 0; m < 4; ++m)
#pragma unroll
      for (int n = 0; n < 8; ++n)
        acc[m][n] = __builtin_amdgcn_mfma_f32_16x16x32_bf16(af[m], bfr[n], acc[m][n], 0, 0, 0);
    __syncthreads();
  }

  const int gn0 = wcn * 128 + l15;
  float bv[8];
#pragma unroll
  for (int n = 0; n < 8; ++n) bv[n] = bias[gn0 + n * 16];
#pragma unroll
  for (int m = 0; m < 4; ++m)
#pragma unroll
    for (int reg = 0; reg < 4; ++reg) {
      int gm = m0 + wr * 64 + m * 16 + lh * 4 + reg;
#pragma unroll
      for (int n = 0; n < 8; ++n)
        C[(size_t)gm * 512 + gn0 + n * 16] = acc[m][n][reg] + bv[n];
    }
}

// ---------------------------------------------------------------------------
// pq/pk GEMM (small): bf16 out. 128x128 tiles, z selects set. Bt is [n][k].
// ---------------------------------------------------------------------------
__global__ __launch_bounds__(256) void gemm_pp(
    const u16* __restrict__ A,
    const u16* __restrict__ Bt0, const float* __restrict__ bi0, u16* __restrict__ C0,
    const u16* __restrict__ Bt1, const float* __restrict__ bi1, u16* __restrict__ C1)
{
  const u16* Bt; const float* bias; u16* C;
  if (blockIdx.z == 0) { Bt = Bt0; bias = bi0; C = C0; }
  else                 { Bt = Bt1; bias = bi1; C = C1; }

  __shared__ u16 As[8192];   // 128 x 64
  __shared__ u16 Bs[8192];   // 128 x 64
  const int tid = threadIdx.x;
  const int lane = tid & 63, wid = tid >> 6;
  const int wr = wid >> 1, wc = wid & 1;
  const int l15 = lane & 15, lh = lane >> 4, l7 = lane & 7;
  const int m0 = blockIdx.x * 128, n0 = blockIdx.y * 128;

  const f32x4 fz = {0.f, 0.f, 0.f, 0.f};
  f32x4 acc[4][4];
#pragma unroll
  for (int m = 0; m < 4; ++m)
#pragma unroll
    for (int n = 0; n < 4; ++n) acc[m][n] = fz;

  int aoff[2], boff[2];
#pragma unroll
  for (int kh = 0; kh < 2; ++kh) {
    int slot = ((kh * 4 + lh) ^ l7) << 4;
    aoff[kh] = (wr * 64 + l15) * 128 + slot;
    boff[kh] = (wc * 64 + l15) * 128 + slot;
  }

  for (int k0 = 0; k0 < 512; k0 += 64) {
    __syncthreads();
#pragma unroll
    for (int it = 0; it < 4; ++it) {
      int L = it * 256 + tid;
      int r = L >> 3, s = L & 7;
      int c = s ^ (r & 7);
      gload_lds16(A  + (size_t)(m0 + r) * 512 + k0 + c * 8,
                  (char*)As + (it * 256 + wid * 64) * 16);
      gload_lds16(Bt + (size_t)(n0 + r) * 512 + k0 + c * 8,
                  (char*)Bs + (it * 256 + wid * 64) * 16);
    }
    __syncthreads();
#pragma unroll
    for (int kh = 0; kh < 2; ++kh) {
      bf16x8 af[4], bfr[4];
#pragma unroll
      for (int m = 0; m < 4; ++m)
        af[m] = *(const bf16x8*)((const char*)As + aoff[kh] + m * 2048);
#pragma unroll
      for (int n = 0; n < 4; ++n)
        bfr[n] = *(const bf16x8*)((const char*)Bs + boff[kh] + n * 2048);
#pragma unroll
      for (int m = 0; m < 4; ++m)
#pragma unroll
        for (int n = 0; n < 4; ++n)
          acc[m][n] = __builtin_amdgcn_mfma_f32_16x16x32_bf16(af[m], bfr[n], acc[m][n], 0, 0, 0);
    }
  }

  const int gn0 = n0 + wc * 64 + l15;
  float bv[4];
#pragma unroll
  for (int n = 0; n < 4; ++n) bv[n] = bias[gn0 + n * 16];
#pragma unroll
  for (int m = 0; m < 4; ++m)
#pragma unroll
    for (int reg = 0; reg < 4; ++reg) {
      int gm = m0 + wr * 64 + m * 16 + lh * 4 + reg;
#pragma unroll
      for (int n = 0; n < 4; ++n)
        C[(size_t)gm * 512 + gn0 + n * 16] = f2b(acc[m][n][reg] + bv[n]);
    }
}

// ---------------------------------------------------------------------------
// qk_mfma: expS[bh][wq][wk] = exp(SCALE * pq_h[wq] . pk_h[wk]) via MFMA.
// ---------------------------------------------------------------------------
__global__ __launch_bounds__(256) void qk_mfma(
    const u16* __restrict__ pq, const u16* __restrict__ pk, u16* __restrict__ expS)
{
  __shared__ u16 As[8192];   // 128 x 64
  __shared__ u16 Bs[8192];
  const int tid = threadIdx.x;
  const int lane = tid & 63, wid = tid >> 6;
  const int wr = wid >> 1, wc = wid & 1;
  const int l15 = lane & 15, lh = lane >> 4, l7 = lane & 7;
  const int bh = blockIdx.z, b = bh >> 3, h = bh & 7;
  const int wq0 = blockIdx.x * 128, wk0 = blockIdx.y * 128;

  const f32x4 fz = {0.f, 0.f, 0.f, 0.f};
  f32x4 acc[4][4];
#pragma unroll
  for (int m = 0; m < 4; ++m)
#pragma unroll
    for (int n = 0; n < 4; ++n) acc[m][n] = fz;

#pragma unroll
  for (int it = 0; it < 4; ++it) {
    int L = it * 256 + tid;
    int r = L >> 3, s = L & 7;
    int c = s ^ (r & 7);
    gload_lds16(pq + ((size_t)b * 512 + wq0 + r) * 512 + h * 64 + c * 8,
                (char*)As + (it * 256 + wid * 64) * 16);
    gload_lds16(pk + ((size_t)b * 512 + wk0 + r) * 512 + h * 64 + c * 8,
                (char*)Bs + (it * 256 + wid * 64) * 16);
  }
  __syncthreads();

#pragma unroll
  for (int kh = 0; kh < 2; ++kh) {
    int slot = ((kh * 4 + lh) ^ l7) << 4;
    int aoff = (wr * 64 + l15) * 128 + slot;
    int boff = (wc * 64 + l15) * 128 + slot;
    bf16x8 af[4], bfr[4];
#pragma unroll
    for (int m = 0; m < 4; ++m)
      af[m] = *(const bf16x8*)((const char*)As + aoff + m * 2048);
#pragma unroll
    for (int n = 0; n < 4; ++n)
      bfr[n] = *(const bf16x8*)((const char*)Bs + boff + n * 2048);
#pragma unroll
    for (int m = 0; m < 4; ++m)
#pragma unroll
      for (int n = 0; n < 4; ++n)
        acc[m][n] = __builtin_amdgcn_mfma_f32_16x16x32_bf16(af[m], bfr[n], acc[m][n], 0, 0, 0);
  }

  const int gn0 = wk0 + wc * 64 + l15;
#pragma unroll
  for (int m = 0; m < 4; ++m)
#pragma unroll
    for (int reg = 0; reg < 4; ++reg) {
      int gm = wq0 + wr * 64 + m * 16 + lh * 4 + reg;
#pragma unroll
      for (int n = 0; n < 4; ++n)
        expS[((size_t)bh * 512 + gm) * 512 + gn0 + n * 16] =
            f2b(expf(acc[m][n][reg] * SCALE_));
    }
}

// ---------------------------------------------------------------------------
// Window attention, all 8 heads per block (512 thr), fused q smoothing AND
// fused LayerNorm+GELU on window token 0. fp32 math in LDS.
// ---------------------------------------------------------------------------
__global__ __launch_bounds__(512) void attn_win(
    const u16* kp, const u16* vp, const u16* qp0, u16* attn,
    const float* lng, const float* lnb, u16* wt)
{
  const int w = blockIdx.x, b = blockIdx.y;
  const int tid = threadIdx.x;
  __shared__ float ks[8][520], vs[8][520], qr[12][520], qs[8][520];
  __shared__ float Ps[8][8][9];
  __shared__ float row0[512];

  const size_t base = ((size_t)b * 4096 + (size_t)w * 8) * 512;

  {
    int i = tid >> 6, dg = tid & 63;
    u16x8 kv = *(const u16x8*)(kp + base + (size_t)i * 512 + dg * 8);
    u16x8 vv = *(const u16x8*)(vp + base + (size_t)i * 512 + dg * 8);
#pragma unroll
    for (int e = 0; e < 8; ++e) {
      ks[i][dg * 8 + e] = b2f(kv[e]);
      vs[i][dg * 8 + e] = b2f(vv[e]);
    }
  }
#pragma unroll
  for (int l = 0; l < 2; ++l) {
    int L = l * 512 + tid;
    if (L < 768) {
      int i = L >> 6, dg = L & 63;
      int m = w * 8 - 2 + i;
      if (m >= 0 && m < 4096) {
        u16x8 qv = *(const u16x8*)(qp0 + ((size_t)b * 4096 + m) * 512 + dg * 8);
#pragma unroll
        for (int e = 0; e < 8; ++e) qr[i][dg * 8 + e] = b2f(qv[e]);
      } else {
#pragma unroll
        for (int e = 0; e < 8; ++e) qr[i][dg * 8 + e] = 0.0f;
      }
    }
  }
  __syncthreads();

  // 5-tap smoothing: thread owns column d = tid, all 8 rows
#pragma unroll
  for (int j = 0; j < 8; ++j)
    qs[j][tid] = 0.2f * (qr[j][tid] + qr[j + 1][tid] + qr[j + 2][tid] +
                         qr[j + 3][tid] + qr[j + 4][tid]);
  __syncthreads();

  // scores: wave h; lane = (qi, kj)
  const int h = tid >> 6;
  const int lane = tid & 63;
  const int qi = lane >> 3, kj = lane & 7;
  float s = 0.0f;
#pragma unroll
  for (int d = 0; d < 64; ++d)
    s = fmaf(qs[qi][h * 64 + d], ks[kj][h * 64 + d], s);
  s *= SCALE_;
  float mx = s;
  mx = fmaxf(mx, __shfl_xor(mx, 1));
  mx = fmaxf(mx, __shfl_xor(mx, 2));
  mx = fmaxf(mx, __shfl_xor(mx, 4));
  float e = expf(s - mx);
  float sum = e;
  sum += __shfl_xor(sum, 1);
  sum += __shfl_xor(sum, 2);
  sum += __shfl_xor(sum, 4);
  Ps[h][qi][kj] = e / sum;
  __syncthreads();

  // PV: lane computes out[qi][h*64 + kj*8 + c]
  float o[8];
#pragma unroll
  for (int c = 0; c < 8; ++c) o[c] = 0.0f;
#pragma unroll
  for (int tt = 0; tt < 8; ++tt) {
    float pw = Ps[h][qi][tt];
#pragma unroll
    for (int c = 0; c < 8; ++c)
      o[c] = fmaf(pw, vs[tt][h * 64 + kj * 8 + c], o[c]);
  }
  u16x8 ov;
#pragma unroll
  for (int c = 0; c < 8; ++c) ov[c] = f2b(o[c]);
  *(u16x8*)(attn + base + (size_t)qi * 512 + h * 64 + kj * 8) = ov;
  if (qi == 0) {
#pragma unroll
    for (int c = 0; c < 8; ++c) row0[h * 64 + kj * 8 + c] = o[c];
  }
  __syncthreads();

  // fused LayerNorm + exact GELU on row 0 (first wave only)
  if (tid < 64) {
    float xv[8];
    float s1 = 0.f, s2 = 0.f;
#pragma unroll
    for (int e2 = 0; e2 < 8; ++e2) {
      xv[e2] = row0[tid * 8 + e2];
      s1 += xv[e2]; s2 += xv[e2] * xv[e2];
    }
#pragma unroll
    for (int off = 1; off < 64; off <<= 1) {
      s1 += __shfl_xor(s1, off);
      s2 += __shfl_xor(s2, off);
    }
    const float mu  = s1 * (1.0f / 512.0f);
    const float var = s2 * (1.0f / 512.0f) - mu * mu;
    const float inv = 1.0f / sqrtf(var + EPS_);
    const int d0 = tid * 8;
    const float k2 = 0.70710678118654752f;
    u16x8 og;
#pragma unroll
    for (int e2 = 0; e2 < 8; ++e2) {
      float y = (xv[e2] - mu) * inv * lng[d0 + e2] + lnb[d0 + e2];
      og[e2] = f2b(0.5f * y * (1.0f + erff(y * k2)));
    }
    *(u16x8*)(wt + ((size_t)b * 512 + w) * 512 + d0) = og;
  }
}

// ---------------------------------------------------------------------------
// Build pvT[bh][n=t*64+d][w2] = attn[b][8*w2+t+1][h*64+d]  (bf16)
// ---------------------------------------------------------------------------
__global__ __launch_bounds__(256) void pvt_build(const u16* attn, u16* pvT)
{
  const int bh = blockIdx.x;
  const int b = bh >> 3, h = bh & 7;
  const int w0 = blockIdx.y * 32;
  __shared__ u16 TL[448 * 40];
  const int tid = threadIdx.x;
#pragma unroll
  for (int it = 0; it < 8; ++it) {
    int L = it * 256 + tid;
    int dg = L & 7, r = L >> 3;
    int w2l = r >> 3, tt = r & 7;
    if (tt < 7) {
      int m = 8 * (w0 + w2l) + tt + 1;
      u16x8 v = *(const u16x8*)(attn + ((size_t)b * 4096 + m) * 512 + h * 64 + dg * 8);
#pragma unroll
      for (int e = 0; e < 8; ++e)
        TL[(tt * 64 + dg * 8 + e) * 40 + w2l] = v[e];
    }
  }
  __syncthreads();
#pragma unroll
  for (int it = 0; it < 7; ++it) {
    int L = it * 256 + tid;
    int n = L >> 2, seg = L & 3;
    u16x8 v = *(const u16x8*)(&TL[n * 40 + seg * 8]);
    *(u16x8*)(pvT + ((size_t)bh * 448 + n) * 512 + w0 + seg * 8) = v;
  }
}

// ---------------------------------------------------------------------------
// rsinv[row] = 1 / sum_k expS[row][k]  (bf16 in). 4 rows per 256-thread block.
// ---------------------------------------------------------------------------
__global__ __launch_bounds__(256) void rs_inv(const u16* expS, float* rsinv)
{
  const int row = blockIdx.x * 4 + (threadIdx.x >> 6);
  const int t = threadIdx.x & 63;
  u16x8 v = *(const u16x8*)(expS + (size_t)row * 512 + t * 8);
  float s = 0.f;
#pragma unroll
  for (int e = 0; e < 8; ++e) s += b2f(v[e]);
#pragma unroll
  for (int off = 1; off < 64; off <<= 1) s += __shfl_xor(s, off);
  if (t == 0) rsinv[row] = 1.0f / s;
}

// ---------------------------------------------------------------------------
// PV MFMA GEMM + rescale + residual. Grid: x = t (7), y = m-strip (4), z = bh.
// ---------------------------------------------------------------------------
__global__ __launch_bounds__(256) void pv_mfma(
    const u16* __restrict__ expS, const u16* __restrict__ pvT,
    const float* __restrict__ rsinv, const u16* __restrict__ attn,
    u16* __restrict__ X2)
{
  __shared__ u16 As[8192];   // 128 x 64
  __shared__ u16 Bs[4096];   // 64 x 64
  const int tid = threadIdx.x;
  const int lane = tid & 63, wid = tid >> 6;
  const int wr = wid >> 1, wc = wid & 1;
  const int l15 = lane & 15, lh = lane >> 4, l7 = lane & 7;
  const int bh = blockIdx.z, b = bh >> 3, h = bh & 7;
  const int m0 = blockIdx.y * 128;
  const int nt = blockIdx.x;           // t in [0,7)

  const f32x4 fz = {0.f, 0.f, 0.f, 0.f};
  f32x4 acc[4][2];
#pragma unroll
  for (int m = 0; m < 4; ++m)
#pragma unroll
    for (int n = 0; n < 2; ++n) acc[m][n] = fz;

  int aoff[2], boff[2];
#pragma unroll
  for (int kh = 0; kh < 2; ++kh) {
    int slot = ((kh * 4 + lh) ^ l7) << 4;
    aoff[kh] = (wr * 64 + l15) * 128 + slot;
    boff[kh] = (wc * 32 + l15) * 128 + slot;
  }

  for (int k0 = 0; k0 < 512; k0 += 64) {
    __syncthreads();
#pragma unroll
    for (int it = 0; it < 4; ++it) {
      int L = it * 256 + tid;
      int r = L >> 3, s = L & 7;
      int c = s ^ (r & 7);
      gload_lds16(expS + ((size_t)bh * 512 + m0 + r) * 512 + k0 + c * 8,
                  (char*)As + (it * 256 + wid * 64) * 16);
    }
#pragma unroll
    for (int it = 0; it < 2; ++it) {
      int L = it * 256 + tid;
      int r = L >> 3, s = L & 7;
      int c = s ^ (r & 7);
      gload_lds16(pvT + ((size_t)bh * 448 + nt * 64 + r) * 512 + k0 + c * 8,
                  (char*)Bs + (it * 256 + wid * 64) * 16);
    }
    __syncthreads();
#pragma unroll
    for (int kh = 0; kh < 2; ++kh) {
      bf16x8 af[4], bfr[2];
#pragma unroll
      for (int m = 0; m < 4; ++m)
        af[m] = *(const bf16x8*)((const char*)As + aoff[kh] + m * 2048);
#pragma unroll
      for (int n = 0; n < 2; ++n)
        bfr[n] = *(const bf16x8*)((const char*)Bs + boff[kh] + n * 2048);
#pragma unroll
      for (int m = 0; m < 4; ++m)
#pragma unroll
        for (int n = 0; n < 2; ++n)
          acc[m][n] = __builtin_amdgcn_mfma_f32_16x16x32_bf16(af[m], bfr[n], acc[m][n], 0, 0, 0);
    }
  }

#pragma unroll
  for (int m = 0; m < 4; ++m)
#pragma unroll
    for (int reg = 0; reg < 4; ++reg) {
      int gm = m0 + wr * 64 + m * 16 + lh * 4 + reg;      // wq
      float ri = rsinv[bh * 512 + gm];
#pragma unroll
      for (int n = 0; n < 2; ++n) {
        int d = wc * 32 + n * 16 + l15;
        float res = b2f(attn[((size_t)b * 4096 + gm * 8 + nt + 1) * 512 + h * 64 + d]);
        X2[((size_t)b * 3584 + gm * 7 + nt) * 512 + h * 64 + d] =
            f2b(acc[m][n][reg] * ri + res);
      }
    }
}

// ---------------------------------------------------------------------------
extern "C" void kernel_launch(void* const* d_in, const int* in_sizes, int n_in,
                              void* d_out, int out_size, void* d_ws, size_t ws_size,
                              hipStream_t stream)
{
  const float* k_in = (const float*)d_in[0];
  const float* v_in = (const float*)d_in[1];
  const float* q_in = (const float*)d_in[2];
  const float* Wk  = (const float*)d_in[4];
  const float* bk  = (const float*)d_in[5];
  const float* Wv  = (const float*)d_in[6];
  const float* bv  = (const float*)d_in[7];
  const float* Wq  = (const float*)d_in[8];
  const float* bq  = (const float*)d_in[9];
  const float* lng = (const float*)d_in[10];
  const float* lnb = (const float*)d_in[11];
  const float* Wpq = (const float*)d_in[12];
  const float* bpq = (const float*)d_in[13];
  const float* Wpk = (const float*)d_in[14];
  const float* bpk = (const float*)d_in[15];
  const float* Wo  = (const float*)d_in[16];
  const float* bo  = (const float*)d_in[17];
  float* out = (float*)d_out;

  char* ws = (char*)d_ws;
  const size_t MB = 1024 * 1024;
  u16* wtb  = (u16*)(ws);                 // 6 x 512KB transposed bf16 weights
  u16* kp   = (u16*)(ws + 16 * MB);
  u16* vp   = (u16*)(ws + 52 * MB);
  u16* qp0  = (u16*)(ws + 88 * MB);
  u16* attn = (u16*)(ws + 124 * MB);
  // phase 2 (kp/vp/qp0 regions reused after attn_win)
  u16*   wt    = (u16*)(ws + 16 * MB);
  u16*   pq    = (u16*)(ws + 20 * MB);
  u16*   pk    = (u16*)(ws + 28 * MB);
  float* rsinv = (float*)(ws + 36 * MB);
  u16*   expS  = (u16*)(ws + 40 * MB);
  u16*   pvT   = (u16*)(ws + 76 * MB);
  u16*   X2    = (u16*)(ws + 160 * MB);

  u16* Wkt  = wtb;
  u16* Wvt  = wtb + 1 * 262144;
  u16* Wqt  = wtb + 2 * 262144;
  u16* Wpqt = wtb + 3 * 262144;
  u16* Wpkt = wtb + 4 * 262144;
  u16* Wot  = wtb + 5 * 262144;

  wconv<<<dim3(8, 8, 6), 256, 0, stream>>>(Wk, Wv, Wq, Wpq, Wpk, Wo, wtb);

  gemm_proj<<<dim3(256, 1, 3), 512, 0, stream>>>(
      k_in, Wkt, bk, kp,
      v_in, Wvt, bv, vp,
      q_in, Wqt, bq, qp0);

  attn_win<<<dim3(512, 8), 512, 0, stream>>>(kp, vp, qp0, attn, lng, lnb, wt);
  pvt_build<<<dim3(64, 16), 256, 0, stream>>>(attn, pvT);

  gemm_pp<<<dim3(32, 4, 2), 256, 0, stream>>>(
      wt, Wpqt, bpq, pq, Wpkt, bpk, pk);

  qk_mfma<<<dim3(4, 4, 64), 256, 0, stream>>>(pq, pk, expS);
  rs_inv<<<8192, 256, 0, stream>>>(expS, rsinv);
  pv_mfma<<<dim3(7, 4, 64), 256, 0, stream>>>(expS, pvT, rsinv, attn, X2);

  gemm_out<<<dim3(224, 1, 1), 512, 0, stream>>>(X2, Wot, bo, out);
}